// Round 10
// baseline (127.445 us; speedup 1.0000x reference)
//
#include <hip/hip_runtime.h>
#include <hip/hip_bf16.h>
#include <stdint.h>

typedef __bf16 bf16x8 __attribute__((ext_vector_type(8)));
typedef __bf16 bf16x4 __attribute__((ext_vector_type(4)));
typedef float  f32x4  __attribute__((ext_vector_type(4)));

static constexpr int Mdim = 2048;   // B*S
static constexpr int Ndim = 4096;   // O
static constexpr int Kdim = 4096;   // I = G*A
static constexpr int DQ_BLOCKS = (Ndim * Kdim / 8) / 256;        // 8192
static constexpr int CVT_BLOCKS = (Mdim * Kdim / 8) / 256;       // 4096

// ---------------- fused prep: dequant W -> bf16 [O][K], cast X -> bf16 [M][K],
// zero split-K combine flags
__global__ __launch_bounds__(256)
void prep(const float* __restrict__ binary, const float* __restrict__ alpha,
          const float* __restrict__ x, __bf16* __restrict__ w,
          __bf16* __restrict__ xb, int* __restrict__ flags) {
  const int b = blockIdx.x;
  const int t = threadIdx.x;
  if (b == 0 && t < 128) flags[t] = 0;
  if (b < DQ_BLOCKS) {
    long e = ((long)b * 256 + t) * 8;       // 8 weights/thread
    int o = (int)(e >> 12);
    int g = (int)((e & 4095) >> 7);
    const float* al = alpha + ((long)o * 32 + g) * 3;
    float a0 = al[0], a1 = al[1], a2 = al[2];
    const float4* q = (const float4*)(binary + e * 3);  // 96B contiguous
    float4 q0 = q[0], q1 = q[1], q2 = q[2], q3 = q[3], q4 = q[4], q5 = q[5];
    bf16x8 wv;
    wv[0] = (__bf16)(a0 * q0.x + a1 * q0.y + a2 * q0.z);
    wv[1] = (__bf16)(a0 * q0.w + a1 * q1.x + a2 * q1.y);
    wv[2] = (__bf16)(a0 * q1.z + a1 * q1.w + a2 * q2.x);
    wv[3] = (__bf16)(a0 * q2.y + a1 * q2.z + a2 * q2.w);
    wv[4] = (__bf16)(a0 * q3.x + a1 * q3.y + a2 * q3.z);
    wv[5] = (__bf16)(a0 * q3.w + a1 * q4.x + a2 * q4.y);
    wv[6] = (__bf16)(a0 * q4.z + a1 * q4.w + a2 * q5.x);
    wv[7] = (__bf16)(a0 * q5.y + a1 * q5.z + a2 * q5.w);
    *(bf16x8*)(w + e) = wv;
  } else {
    long e = ((long)(b - DQ_BLOCKS) * 256 + t) * 8;
    float4 v0 = *(const float4*)(x + e);
    float4 v1 = *(const float4*)(x + e + 4);
    bf16x8 r;
    r[0] = (__bf16)v0.x; r[1] = (__bf16)v0.y; r[2] = (__bf16)v0.z; r[3] = (__bf16)v0.w;
    r[4] = (__bf16)v1.x; r[5] = (__bf16)v1.y; r[6] = (__bf16)v1.z; r[7] = (__bf16)v1.w;
    *(bf16x8*)(xb + e) = r;
  }
}

// ---------------- 256x256 split-K=2 GEMM, 8 waves (2Mx4N, wave 128x64),
// BK=64, double-buffered LDS (128KB), 8 phases / 2 tiles, GATE(8) steady.
// Fused split-K combine: partials per-slice (ks*128+tile); 2nd arriver adds
// PARTNER slice (agent-scope atomic loads) + bias, writes out once.
static constexpr int KSLICE = 2048;
static constexpr int NT = KSLICE / 64;   // 32 K-tiles per slice
static constexpr int HB = 65536;         // bytes per buffer (A 32KB + B 32KB)

__device__ __forceinline__ void g2l16(const void* g, void* l) {
  __builtin_amdgcn_global_load_lds(
      (const __attribute__((address_space(1))) void*)g,
      (__attribute__((address_space(3))) void*)l, 16, 0, 0);
}

#define BAR()    __builtin_amdgcn_s_barrier()
#define LGKM0()  asm volatile("s_waitcnt lgkmcnt(0)" ::: "memory")
#define SCHED0() __builtin_amdgcn_sched_barrier(0)
#define GATE8()  asm volatile("s_waitcnt vmcnt(8)" ::: "memory")
#define GATE0()  asm volatile("s_waitcnt vmcnt(0)" ::: "memory")

// Stage units (2 x g2l16 each).  LDS linear dest; source pre-swizzled
// (granule ^= row&7) so read-side XOR matches. [rule 21]
#define STAGE_A1(t, bo) do { \
  g2l16(baseA +                 (long)(t) * 64, sm + (bo) +     0 + w * 1024); \
  g2l16(baseA + 128L * Kdim   + (long)(t) * 64, sm + (bo) + 16384 + w * 1024); \
} while (0)
#define STAGE_A2(t, bo) do { \
  g2l16(baseA +  64L * Kdim   + (long)(t) * 64, sm + (bo) +  8192 + w * 1024); \
  g2l16(baseA + 192L * Kdim   + (long)(t) * 64, sm + (bo) + 24576 + w * 1024); \
} while (0)
#define STAGE_B1(t, bo) do { \
  g2l16(baseB +                 (long)(t) * 64, sm + (bo) + 32768 + bq * 1024); \
  g2l16(baseB +   8L * Kdim   + (long)(t) * 64, sm + (bo) + 32768 + bq * 1024 + 1024); \
} while (0)
#define STAGE_B2(t, bo) do { \
  g2l16(baseB +  32L * Kdim   + (long)(t) * 64, sm + (bo) + 32768 + bq * 1024 + 4096); \
  g2l16(baseB +  40L * Kdim   + (long)(t) * 64, sm + (bo) + 32768 + bq * 1024 + 5120); \
} while (0)

#define LOAD_A4(dst, bo, m0_) do { \
  _Pragma("unroll") for (int m_ = 0; m_ < 4; ++m_) \
    _Pragma("unroll") for (int h_ = 0; h_ < 2; ++h_) \
      dst[m_][h_] = *(const bf16x8*)(sm + (bo) + aoffbase + ((m0_) + m_) * 2048 + swz[h_]); \
} while (0)
#define LOAD_B2(dst, bo, n0_) do { \
  _Pragma("unroll") for (int n_ = 0; n_ < 2; ++n_) \
    _Pragma("unroll") for (int h_ = 0; h_ < 2; ++h_) \
      dst[n_][h_] = *(const bf16x8*)(sm + (bo) + boffbase + ((n0_) + n_) * 2048 + swz[h_]); \
} while (0)

#define MMA8(fa_, fb_, m0_, n0_) do { \
  __builtin_amdgcn_s_setprio(1); \
  _Pragma("unroll") for (int m_ = 0; m_ < 4; ++m_) \
    _Pragma("unroll") for (int n_ = 0; n_ < 2; ++n_) { \
      acc[(m0_) + m_][(n0_) + n_] = __builtin_amdgcn_mfma_f32_16x16x32_bf16( \
          fa_[m_][0], fb_[n_][0], acc[(m0_) + m_][(n0_) + n_], 0, 0, 0); \
      acc[(m0_) + m_][(n0_) + n_] = __builtin_amdgcn_mfma_f32_16x16x32_bf16( \
          fa_[m_][1], fb_[n_][1], acc[(m0_) + m_][(n0_) + n_], 0, 0, 0); \
    } \
  __builtin_amdgcn_s_setprio(0); \
} while (0)

#define KTILE(t_, bo, PF_, LASTGATE) do { \
  /* P1 */ \
  LOAD_A4(fa, bo, 0); LOAD_B2(fb01, bo, 0); \
  BAR(); LGKM0(); SCHED0(); \
  MMA8(fa, fb01, 0, 0); \
  BAR(); \
  /* P2 */ \
  LOAD_B2(fb23, bo, 2); \
  if (PF_) { STAGE_A1((t_) + 2, bo); STAGE_B1((t_) + 2, bo); } \
  BAR(); LGKM0(); SCHED0(); \
  MMA8(fa, fb23, 0, 2); \
  BAR(); \
  /* P3 */ \
  LOAD_A4(fa, bo, 4); \
  if (PF_) STAGE_B2((t_) + 2, bo); \
  BAR(); LGKM0(); SCHED0(); \
  MMA8(fa, fb01, 4, 0); \
  BAR(); \
  /* P4 */ \
  if (PF_) { STAGE_A2((t_) + 2, bo); GATE8(); } else { LASTGATE; } \
  BAR(); \
  MMA8(fa, fb23, 4, 2); \
  BAR(); \
} while (0)

__global__ __launch_bounds__(512, 2)
void gemm256(const __bf16* __restrict__ A, const __bf16* __restrict__ Bw,
             __bf16* __restrict__ PP, int* __restrict__ flags,
             const float* __restrict__ bias, float* __restrict__ out) {
  __shared__ __align__(128) char sm[2 * HB];   // 128 KB
  __shared__ int role_sh;
  const int tid = threadIdx.x, lane = tid & 63, w = tid >> 6;
  const int wm = w >> 2, wn = w & 3;           // wave tile 128x64

  const int bid = blockIdx.x;
  const int logical = (bid & 7) * 32 + (bid >> 3);
  const int ks = logical >> 7;                 // split-K slice
  const int tile = logical & 127;
  const int tm = tile & 7, tn = tile >> 3;     // 8 x 16 tiles of 256x256
  const int kbase = ks * KSLICE;

  const int rlo = lane >> 3;
  const int gsw = (lane & 7) ^ rlo;
  const __bf16* baseA = A + (long)(tm * 256 + w * 8 + rlo) * Kdim + kbase + gsw * 8;
  const __bf16* baseB = Bw + (long)(tn * 256 + (w >> 1) * 64 + (w & 1) * 16 + rlo) * Kdim
                        + kbase + gsw * 8;
  const int bq = (w >> 1) * 8 + (w & 1) * 2;

  int swz[2];
#pragma unroll
  for (int h = 0; h < 2; ++h)
    swz[h] = (((h * 4 + (lane >> 4)) ^ (lane & 7)) << 4);
  const int aoffbase = (wm * 128 + (lane & 15)) * 128;
  const int boffbase = 32768 + (wn * 64 + (lane & 15)) * 128;

  f32x4 acc[8][4] = {};
  bf16x8 fa[4][2], fb01[2][2], fb23[2][2];

  STAGE_A1(0, 0);  STAGE_B1(0, 0);  STAGE_B2(0, 0);  STAGE_A2(0, 0);
  STAGE_A1(1, HB); STAGE_B1(1, HB); STAGE_B2(1, HB); STAGE_A2(1, HB);
  GATE8();
  BAR();

  for (int i = 0; i < NT / 2; ++i) {
    const int t0 = 2 * i, t1 = 2 * i + 1;
    const bool pf = (i < NT / 2 - 1);
    KTILE(t0, 0,  pf, GATE0());
    KTILE(t1, HB, pf, GATE0());
  }

  // ---- fused split-K combine (per-slice partials!) ----
  // my slice = ks*128+tile ; partner slice = (1-ks)*128+tile
  __bf16* pmy = PP + ((long)ks * 128 + tile) * 65536;
  const __bf16* ppt = PP + ((long)(1 - ks) * 128 + tile) * 65536;
  // 1) store my partial as bf16x4/thread/quad, lane-blocked coalesced
#pragma unroll
  for (int m = 0; m < 8; ++m)
#pragma unroll
    for (int n = 0; n < 4; ++n) {
      bf16x4 pv;
#pragma unroll
      for (int r = 0; r < 4; ++r) pv[r] = (__bf16)acc[m][n][r];
      *(bf16x4*)(pmy + (long)(m * 4 + n) * 2048 + tid * 4) = pv;
    }
  GATE0();                 // my stores complete
  BAR();                   // all threads' stores complete
  if (tid == 0)
    role_sh = (int)__hip_atomic_fetch_add(&flags[tile], 1, __ATOMIC_ACQ_REL,
                                          __HIP_MEMORY_SCOPE_AGENT);
  BAR();
  if (role_sh == 0) return;   // first arriver: partner combines

  // 2) second arriver: add partner partial via agent-scope atomic loads
  //    (coherent path; immune to stale lines in this XCD's caches)
#pragma unroll
  for (int m = 0; m < 8; ++m)
#pragma unroll
    for (int n = 0; n < 4; ++n) {
      unsigned long long u = __hip_atomic_load(
          (const unsigned long long*)(ppt + (long)(m * 4 + n) * 2048 + tid * 4),
          __ATOMIC_RELAXED, __HIP_MEMORY_SCOPE_AGENT);
      bf16x4 pv = *(bf16x4*)&u;
#pragma unroll
      for (int r = 0; r < 4; ++r) acc[m][n][r] += (float)pv[r];
    }

  // 3) LDS-transposed coalesced out-write with fused bias, 4 chunks of 64 rows
  float* lf = (float*)sm;
  const int r4 = (lane >> 4) * 4;
  const int cl = lane & 15;
  for (int c = 0; c < 4; ++c) {
    if (wm == (c >> 1)) {
      const int mlo = (c & 1) * 4;
#pragma unroll
      for (int mm = 0; mm < 4; ++mm)
#pragma unroll
        for (int n = 0; n < 4; ++n)
#pragma unroll
          for (int r = 0; r < 4; ++r) {
            int rowc = mm * 16 + r4 + r;           // 0..63
            int col = wn * 64 + n * 16 + cl;
            lf[rowc * 260 + col] = acc[mlo + mm][n][r];
          }
    }
    __syncthreads();
#pragma unroll
    for (int i = 0; i < 8; ++i) {
      int idx = tid + i * 512;                     // 4096 f32x4 chunks
      int rowc = idx >> 6;
      int c4 = idx & 63;
      f32x4 v = *(const f32x4*)(lf + rowc * 260 + c4 * 4);
      float4 bv = *(const float4*)(bias + tn * 256 + c4 * 4);
      v[0] += bv.x; v[1] += bv.y; v[2] += bv.z; v[3] += bv.w;
      *(f32x4*)(out + (long)(tm * 256 + c * 64 + rowc) * Ndim + tn * 256 + c4 * 4) = v;
    }
    __syncthreads();
  }
}

extern "C" void kernel_launch(void* const* d_in, const int* in_sizes, int n_in,
                              void* d_out, int out_size, void* d_ws, size_t ws_size,
                              hipStream_t stream) {
  const float* x      = (const float*)d_in[0];
  const float* binary = (const float*)d_in[1];
  const float* alpha  = (const float*)d_in[2];
  const float* bias   = (const float*)d_in[3];
  float* out = (float*)d_out;

  __bf16* wb = (__bf16*)d_ws;                              // 32 MB  W bf16 [N][K]
  __bf16* xb = wb + (size_t)Ndim * Kdim;                   // 16 MB  X bf16 [M][K]
  __bf16* pp = xb + (size_t)Mdim * Kdim;                   // 32 MB  bf16 partials [256][65536]
  int*    fl = (int*)(pp + (size_t)256 * 65536);           // 512 B flags

  prep<<<dim3(DQ_BLOCKS + CVT_BLOCKS), 256, 0, stream>>>(binary, alpha, x, wb, xb, fl);
  gemm256<<<dim3(256), 512, 0, stream>>>(xb, wb, pp, fl, bias, out);
}